// Round 10
// baseline (27.355 us; speedup 1.0000x reference)
//
#include <hip/hip_runtime.h>
#include <stdint.h>

typedef __attribute__((ext_vector_type(8))) short short8;
typedef __attribute__((ext_vector_type(4))) float f32x4;
typedef __attribute__((ext_vector_type(2))) unsigned int u32x2;

#define SEQ 256
#define NH 8

__device__ __forceinline__ uint32_t cvt_pk_bf16(float lo, float hi) {
  uint32_t r;
  asm("v_cvt_pk_bf16_f32 %0, %1, %2" : "=v"(r) : "v"(lo), "v"(hi));
  return r;
}

__device__ __forceinline__ short8 pack8(f32x4 a, f32x4 b) {
  union { uint32_t u[4]; short8 v; } t;
  t.u[0] = cvt_pk_bf16(a[0], a[1]);
  t.u[1] = cvt_pk_bf16(a[2], a[3]);
  t.u[2] = cvt_pk_bf16(b[0], b[1]);
  t.u[3] = cvt_pk_bf16(b[2], b[3]);
  return t.v;
}

// x[lane] + x[lane^16] via permlane16_swap self-swap (VALU pipe, no lgkm)
__device__ __forceinline__ float xorsum16(float x) {
#if __has_builtin(__builtin_amdgcn_permlane16_swap)
  unsigned ux = __builtin_bit_cast(unsigned, x);
  auto r = __builtin_amdgcn_permlane16_swap(ux, ux, false, false);
  return __builtin_bit_cast(float, (unsigned)r[0]) +
         __builtin_bit_cast(float, (unsigned)r[1]);
#else
  return x + __shfl_xor(x, 16, 64);
#endif
}
// x[lane] + x[lane^32]
__device__ __forceinline__ float xorsum32(float x) {
#if __has_builtin(__builtin_amdgcn_permlane32_swap)
  unsigned ux = __builtin_bit_cast(unsigned, x);
  auto r = __builtin_amdgcn_permlane32_swap(ux, ux, false, false);
  return __builtin_bit_cast(float, (unsigned)r[0]) +
         __builtin_bit_cast(float, (unsigned)r[1]);
#else
  return x + __shfl_xor(x, 32, 64);
#endif
}

// ---------------------------------------------------------------------------
// ONE fused kernel (r7 structure; permlane-swap tail instead of ds_bpermute).
// Block = (b, h, 64m x 64n), 512 thr (8 waves), 512 blocks.
// Phase 1 (validated r5): build pre-ReLU layer-1 tables via MFMA into LDS:
//   sAp[rl][k] (rl=m-n+63, 128 rows, row127 junk), sAi[64], sAj[64].
// Phase 2 per ng-group: batch-load Apos operands; 4 independent chains
//   e1=relu(Ap+Ai+Aj)->bf16 -> mfma32(A=w2^T) -> e2^T -> relu-dot w3;
//   reduce: S_j = xorsum32(xorsum16(part[j])) (pure VALU), select S[kb]
//   (validated r5 select), coalesced attn-add store.
// ---------------------------------------------------------------------------
__global__ __launch_bounds__(512, 4) void dis_att_fused(
    const float* __restrict__ attn, const int* __restrict__ bseq,
    const int* __restrict__ cseq, const float* __restrict__ epos,
    const float* __restrict__ ebi, const float* __restrict__ ebj,
    const float* __restrict__ eci, const float* __restrict__ ecj,
    const float* __restrict__ w1, const float* __restrict__ w2,
    const float* __restrict__ w3, float* __restrict__ out) {
  __shared__ float sAp[128][36];
  __shared__ float sAi[64][36];
  __shared__ float sAj[64][36];
  int tid = threadIdx.x;
  int wg = blockIdx.x;                     // 512 = b(4) h(8) mt(4) nt(4)
  int nt = wg & 3, mt = (wg >> 2) & 3, h = (wg >> 4) & 7, b = wg >> 7;
  int m0 = mt * 64, n0 = nt * 64;
  int f0 = m0 - n0 + 193;                  // global f of sAp row 0
  int lane = tid & 63, w = tid >> 6;
  int lcol = lane & 15, kb = lane >> 4, k8 = kb * 8;
  f32x4 zero = {0.f, 0.f, 0.f, 0.f};

  // ---------------- phase 1: build tables (validated r5) ----------------
  if (w < 4) {                             // Apos band: m-tiles {w, w+4} x kk{0,1}
    short8 bf[2];
#pragma unroll
    for (int kt = 0; kt < 2; ++kt) {       // B = W_pos[k=p][kk]
      union { uint32_t u[4]; short8 v; } t;
#pragma unroll
      for (int r = 0; r < 4; ++r) {
        float lo = w1[(k8 + 2 * r) * 256 + (kt * 16 + lcol) * 8 + h];
        float hi = w1[(k8 + 2 * r + 1) * 256 + (kt * 16 + lcol) * 8 + h];
        t.u[r] = cvt_pk_bf16(lo, hi);
      }
      bf[kt] = t.v;
    }
#pragma unroll
    for (int t = 0; t < 2; ++t) {
      int mt_ = w + t * 4;                 // tile 0..7 (rows mt_*16..+15)
      int frow = f0 + mt_ * 16 + lcol;
      if (frow > 511) frow = 511;          // row 127 junk, never read
      const float* ep = epos + (frow * NH + h) * 32 + k8;
      short8 af = pack8(*(const f32x4*)ep, *(const f32x4*)(ep + 4));
#pragma unroll
      for (int kt = 0; kt < 2; ++kt) {
        f32x4 d = __builtin_amdgcn_mfma_f32_16x16x32_bf16(af, bf[kt], zero, 0, 0, 0);
#pragma unroll
        for (int r = 0; r < 4; ++r)
          sAp[mt_ * 16 + kb * 4 + r][kt * 16 + lcol] = d[r];
      }
    }
  } else {                                 // Ai (waves 4,5) / Aj (waves 6,7)
    int isI = w < 6;
    int p0 = isI ? ((kb < 2 ? 32 : 48) + k8)    // W_i rows: 32..47 | 64..79
                 : ((kb < 2 ? 48 : 64) + k8);   // W_j rows: 48..63 | 80..95
    short8 bf[2];
#pragma unroll
    for (int kt = 0; kt < 2; ++kt) {
      union { uint32_t u[4]; short8 v; } t;
#pragma unroll
      for (int r = 0; r < 4; ++r) {
        float lo = w1[(p0 + 2 * r) * 256 + (kt * 16 + lcol) * 8 + h];
        float hi = w1[(p0 + 2 * r + 1) * 256 + (kt * 16 + lcol) * 8 + h];
        t.u[r] = cvt_pk_bf16(lo, hi);
      }
      bf[kt] = t.v;
    }
    const float* eB = isI ? ebi : ebj;
    const float* eC = isI ? eci : ecj;
    int base = isI ? m0 : n0;
    int w2_ = isI ? (w - 4) : (w - 6);
#pragma unroll
    for (int t = 0; t < 2; ++t) {
      int mt_ = w2_ * 2 + t;               // tile 0..3 (rows mt_*16..+15)
      int gm = b * SEQ + base + mt_ * 16 + lcol;
      int bi = bseq[gm], ci = cseq[gm];
      const float* src = (kb < 2) ? eB + (bi * NH + h) * 16 + k8
                                  : eC + (ci * NH + h) * 16 + (k8 - 16);
      short8 af = pack8(*(const f32x4*)src, *(const f32x4*)(src + 4));
#pragma unroll
      for (int kt = 0; kt < 2; ++kt) {
        f32x4 d = __builtin_amdgcn_mfma_f32_16x16x32_bf16(af, bf[kt], zero, 0, 0, 0);
#pragma unroll
        for (int r = 0; r < 4; ++r) {
          float* T = isI ? &sAi[mt_ * 16 + kb * 4 + r][kt * 16 + lcol]
                         : &sAj[mt_ * 16 + kb * 4 + r][kt * 16 + lcol];
          *T = d[r];
        }
      }
    }
  }
  __syncthreads();

  // ---------------- phase 2: main compute ----------------
  union { uint32_t u[4]; short8 v; } w2f;  // A = w2^T: row=lcol, k=k8..k8+7
#pragma unroll
  for (int r = 0; r < 4; ++r) {
    float lo = w2[(k8 + 2 * r) * 128 + lcol * 8 + h];
    float hi = w2[(k8 + 2 * r + 1) * 128 + lcol * 8 + h];
    w2f.u[r] = cvt_pk_bf16(lo, hi);
  }
  float w3v[4];
#pragma unroll
  for (int r = 0; r < 4; ++r) w3v[r] = w3[(kb * 4 + r) * 8 + h];

  // hoist Aj for all 4 ng (constant across both s-steps)
  f32x4 ajA[4], ajB[4];
#pragma unroll
  for (int ng = 0; ng < 4; ++ng) {
    int nl = ng * 16 + lcol;
    ajA[ng] = *(const f32x4*)&sAj[nl][k8];
    ajB[ng] = *(const f32x4*)&sAj[nl][k8 + 4];
  }

  const float* attn_b = attn + (b * NH + h) * SEQ * SEQ;
  float* out_b = out + (b * NH + h) * SEQ * SEQ;
  int bit4 = kb & 1, bit5 = kb & 2;

#pragma unroll
  for (int s = 0; s < 2; ++s) {
    int mb = w * 8 + s * 4;
    float av[4];
    int idxs[4];
#pragma unroll
    for (int ng = 0; ng < 4; ++ng) {
      idxs[ng] = (m0 + mb + kb) * SEQ + n0 + ng * 16 + lcol;
      av[ng] = attn_b[idxs[ng]];
    }
    // Ai rows for this s-step's 4 m's
    f32x4 aiA[4], aiB[4];
#pragma unroll
    for (int mi = 0; mi < 4; ++mi) {
      aiA[mi] = *(const f32x4*)&sAi[mb + mi][k8];
      aiB[mi] = *(const f32x4*)&sAi[mb + mi][k8 + 4];
    }
#pragma unroll
    for (int ng = 0; ng < 4; ++ng) {
      int nl = ng * 16 + lcol;
      // batch-load all Apos operands for the 4 chains
      f32x4 pA[4], pB[4];
#pragma unroll
      for (int mi = 0; mi < 4; ++mi) {
        int rl = mb + mi - nl + 63;
        pA[mi] = *(const f32x4*)&sAp[rl][k8];
        pB[mi] = *(const f32x4*)&sAp[rl][k8 + 4];
      }
      __builtin_amdgcn_sched_barrier(0);
      float part[4];
#pragma unroll
      for (int mi = 0; mi < 4; ++mi) {
        f32x4 s0 = pA[mi] + aiA[mi] + ajA[ng];
        f32x4 s1 = pB[mi] + aiB[mi] + ajB[ng];
        union { uint32_t u[4]; short8 v; } ef;
        ef.u[0] = cvt_pk_bf16(fmaxf(s0[0], 0.f), fmaxf(s0[1], 0.f));
        ef.u[1] = cvt_pk_bf16(fmaxf(s0[2], 0.f), fmaxf(s0[3], 0.f));
        ef.u[2] = cvt_pk_bf16(fmaxf(s1[0], 0.f), fmaxf(s1[1], 0.f));
        ef.u[3] = cvt_pk_bf16(fmaxf(s1[2], 0.f), fmaxf(s1[3], 0.f));
        f32x4 d = __builtin_amdgcn_mfma_f32_16x16x32_bf16(w2f.v, ef.v, zero, 0, 0, 0);
        part[mi] = fmaxf(d[0], 0.f) * w3v[0] + fmaxf(d[1], 0.f) * w3v[1] +
                   fmaxf(d[2], 0.f) * w3v[2] + fmaxf(d[3], 0.f) * w3v[3];
      }
      // quarter-sum each chain via permlane self-swaps (VALU only), then
      // select chain kb (validated r5 mapping: lane(kb,lcol) owns m=mb+kb)
      float S0 = xorsum32(xorsum16(part[0]));
      float S1 = xorsum32(xorsum16(part[1]));
      float S2 = xorsum32(xorsum16(part[2]));
      float S3 = xorsum32(xorsum16(part[3]));
      float p01 = bit4 ? S1 : S0;
      float p23 = bit4 ? S3 : S2;
      float pf = bit5 ? p23 : p01;
      out_b[idxs[ng]] = av[ng] + pf;
    }
  }
}

extern "C" void kernel_launch(void* const* d_in, const int* in_sizes, int n_in,
                              void* d_out, int out_size, void* d_ws, size_t ws_size,
                              hipStream_t stream) {
  const float* attn = (const float*)d_in[0];
  const int* bseq   = (const int*)d_in[1];
  const int* cseq   = (const int*)d_in[2];
  const float* epos = (const float*)d_in[3];
  const float* ebi  = (const float*)d_in[4];
  const float* ebj  = (const float*)d_in[5];
  const float* eci  = (const float*)d_in[6];
  const float* ecj  = (const float*)d_in[7];
  const float* w1   = (const float*)d_in[8];
  const float* w2   = (const float*)d_in[9];
  const float* w3   = (const float*)d_in[10];
  float* out = (float*)d_out;

  hipLaunchKernelGGL(dis_att_fused, dim3(512), dim3(512), 0, stream,
                     attn, bseq, cseq, epos, ebi, ebj, eci, ecj, w1, w2, w3, out);
}

// Round 11
// 26.803 us; speedup vs baseline: 1.0206x; 1.0206x over previous
//
#include <hip/hip_runtime.h>
#include <stdint.h>

typedef __attribute__((ext_vector_type(8))) short short8;
typedef __attribute__((ext_vector_type(4))) float f32x4;

#define SEQ 256
#define NH 8

__device__ __forceinline__ uint32_t cvt_pk_bf16(float lo, float hi) {
  uint32_t r;
  asm("v_cvt_pk_bf16_f32 %0, %1, %2" : "=v"(r) : "v"(lo), "v"(hi));
  return r;
}

__device__ __forceinline__ short8 pack8(f32x4 a, f32x4 b) {
  union { uint32_t u[4]; short8 v; } t;
  t.u[0] = cvt_pk_bf16(a[0], a[1]);
  t.u[1] = cvt_pk_bf16(a[2], a[3]);
  t.u[2] = cvt_pk_bf16(b[0], b[1]);
  t.u[3] = cvt_pk_bf16(b[2], b[3]);
  return t.v;
}

// ---------------------------------------------------------------------------
// ONE fused kernel (r7 math; cross-group pipelined phase 2, deep-ILP regime).
// Block = (b, h, 64m x 64n), 512 thr (8 waves), 512 blocks.
// launch_bounds(512,2): 256-VGPR budget, 1 block/CU, 2 waves/SIMD -- few fat
// waves; the ng-loop double-buffers pA/pB register sets so group g+1's 8
// ds_read_b128 issue before group g's compute (LDS latency hidden under the
// previous group's VALU+MFMA).
// Phase 1 (validated r5): build pre-ReLU layer-1 tables via MFMA into LDS:
//   sAp[rl][k] (rl=m-n+63, 128 rows, row127 junk), sAi[64], sAj[64].
// ---------------------------------------------------------------------------
__global__ __launch_bounds__(512, 2) void dis_att_fused(
    const float* __restrict__ attn, const int* __restrict__ bseq,
    const int* __restrict__ cseq, const float* __restrict__ epos,
    const float* __restrict__ ebi, const float* __restrict__ ebj,
    const float* __restrict__ eci, const float* __restrict__ ecj,
    const float* __restrict__ w1, const float* __restrict__ w2,
    const float* __restrict__ w3, float* __restrict__ out) {
  __shared__ float sAp[128][36];
  __shared__ float sAi[64][36];
  __shared__ float sAj[64][36];
  int tid = threadIdx.x;
  int wg = blockIdx.x;                     // 512 = b(4) h(8) mt(4) nt(4)
  int nt = wg & 3, mt = (wg >> 2) & 3, h = (wg >> 4) & 7, b = wg >> 7;
  int m0 = mt * 64, n0 = nt * 64;
  int f0 = m0 - n0 + 193;                  // global f of sAp row 0
  int lane = tid & 63, w = tid >> 6;
  int lcol = lane & 15, kb = lane >> 4, k8 = kb * 8;
  f32x4 zero = {0.f, 0.f, 0.f, 0.f};

  // ---------------- phase 1: build tables (validated r5) ----------------
  if (w < 4) {                             // Apos band: m-tiles {w, w+4} x kk{0,1}
    short8 bf[2];
#pragma unroll
    for (int kt = 0; kt < 2; ++kt) {       // B = W_pos[k=p][kk]
      union { uint32_t u[4]; short8 v; } t;
#pragma unroll
      for (int r = 0; r < 4; ++r) {
        float lo = w1[(k8 + 2 * r) * 256 + (kt * 16 + lcol) * 8 + h];
        float hi = w1[(k8 + 2 * r + 1) * 256 + (kt * 16 + lcol) * 8 + h];
        t.u[r] = cvt_pk_bf16(lo, hi);
      }
      bf[kt] = t.v;
    }
#pragma unroll
    for (int t = 0; t < 2; ++t) {
      int mt_ = w + t * 4;                 // tile 0..7 (rows mt_*16..+15)
      int frow = f0 + mt_ * 16 + lcol;
      if (frow > 511) frow = 511;          // row 127 junk, never read
      const float* ep = epos + (frow * NH + h) * 32 + k8;
      short8 af = pack8(*(const f32x4*)ep, *(const f32x4*)(ep + 4));
#pragma unroll
      for (int kt = 0; kt < 2; ++kt) {
        f32x4 d = __builtin_amdgcn_mfma_f32_16x16x32_bf16(af, bf[kt], zero, 0, 0, 0);
#pragma unroll
        for (int r = 0; r < 4; ++r)
          sAp[mt_ * 16 + kb * 4 + r][kt * 16 + lcol] = d[r];
      }
    }
  } else {                                 // Ai (waves 4,5) / Aj (waves 6,7)
    int isI = w < 6;
    int p0 = isI ? ((kb < 2 ? 32 : 48) + k8)    // W_i rows: 32..47 | 64..79
                 : ((kb < 2 ? 48 : 64) + k8);   // W_j rows: 48..63 | 80..95
    short8 bf[2];
#pragma unroll
    for (int kt = 0; kt < 2; ++kt) {
      union { uint32_t u[4]; short8 v; } t;
#pragma unroll
      for (int r = 0; r < 4; ++r) {
        float lo = w1[(p0 + 2 * r) * 256 + (kt * 16 + lcol) * 8 + h];
        float hi = w1[(p0 + 2 * r + 1) * 256 + (kt * 16 + lcol) * 8 + h];
        t.u[r] = cvt_pk_bf16(lo, hi);
      }
      bf[kt] = t.v;
    }
    const float* eB = isI ? ebi : ebj;
    const float* eC = isI ? eci : ecj;
    int base = isI ? m0 : n0;
    int w2_ = isI ? (w - 4) : (w - 6);
#pragma unroll
    for (int t = 0; t < 2; ++t) {
      int mt_ = w2_ * 2 + t;               // tile 0..3 (rows mt_*16..+15)
      int gm = b * SEQ + base + mt_ * 16 + lcol;
      int bi = bseq[gm], ci = cseq[gm];
      const float* src = (kb < 2) ? eB + (bi * NH + h) * 16 + k8
                                  : eC + (ci * NH + h) * 16 + (k8 - 16);
      short8 af = pack8(*(const f32x4*)src, *(const f32x4*)(src + 4));
#pragma unroll
      for (int kt = 0; kt < 2; ++kt) {
        f32x4 d = __builtin_amdgcn_mfma_f32_16x16x32_bf16(af, bf[kt], zero, 0, 0, 0);
#pragma unroll
        for (int r = 0; r < 4; ++r) {
          float* T = isI ? &sAi[mt_ * 16 + kb * 4 + r][kt * 16 + lcol]
                         : &sAj[mt_ * 16 + kb * 4 + r][kt * 16 + lcol];
          *T = d[r];
        }
      }
    }
  }
  __syncthreads();

  // ---------------- phase 2: main compute (pipelined groups) ----------------
  union { uint32_t u[4]; short8 v; } w2f;  // A = w2^T: row=lcol, k=k8..k8+7
#pragma unroll
  for (int r = 0; r < 4; ++r) {
    float lo = w2[(k8 + 2 * r) * 128 + lcol * 8 + h];
    float hi = w2[(k8 + 2 * r + 1) * 128 + lcol * 8 + h];
    w2f.u[r] = cvt_pk_bf16(lo, hi);
  }
  float w3v[4];
#pragma unroll
  for (int r = 0; r < 4; ++r) w3v[r] = w3[(kb * 4 + r) * 8 + h];

  // hoist Aj for all 4 ng (constant across both s-steps)
  f32x4 ajA[4], ajB[4];
#pragma unroll
  for (int ng = 0; ng < 4; ++ng) {
    int nl = ng * 16 + lcol;
    ajA[ng] = *(const f32x4*)&sAj[nl][k8];
    ajB[ng] = *(const f32x4*)&sAj[nl][k8 + 4];
  }

  const float* attn_b = attn + (b * NH + h) * SEQ * SEQ;
  float* out_b = out + (b * NH + h) * SEQ * SEQ;
  int bit4 = kb & 1, bit5 = kb & 2;

#pragma unroll
  for (int s = 0; s < 2; ++s) {
    int mb = w * 8 + s * 4;
    float av[4];
    int idxs[4];
#pragma unroll
    for (int ng = 0; ng < 4; ++ng) {
      idxs[ng] = (m0 + mb + kb) * SEQ + n0 + ng * 16 + lcol;
      av[ng] = attn_b[idxs[ng]];
    }
    // Ai rows for this s-step's 4 m's
    f32x4 aiA[4], aiB[4];
#pragma unroll
    for (int mi = 0; mi < 4; ++mi) {
      aiA[mi] = *(const f32x4*)&sAi[mb + mi][k8];
      aiB[mi] = *(const f32x4*)&sAi[mb + mi][k8 + 4];
    }
    // double-buffered Apos operand sets; prologue: load set 0 (ng=0)
    f32x4 pA[2][4], pB[2][4];
#pragma unroll
    for (int mi = 0; mi < 4; ++mi) {
      int rl = mb + mi - lcol + 63;
      pA[0][mi] = *(const f32x4*)&sAp[rl][k8];
      pB[0][mi] = *(const f32x4*)&sAp[rl][k8 + 4];
    }
#pragma unroll
    for (int ng = 0; ng < 4; ++ng) {
      int cur = ng & 1, nxt = cur ^ 1;
      if (ng < 3) {                        // prefetch next group's operands
        int nl2 = (ng + 1) * 16 + lcol;
#pragma unroll
        for (int mi = 0; mi < 4; ++mi) {
          int rl = mb + mi - nl2 + 63;
          pA[nxt][mi] = *(const f32x4*)&sAp[rl][k8];
          pB[nxt][mi] = *(const f32x4*)&sAp[rl][k8 + 4];
        }
      }
      float part[4];
#pragma unroll
      for (int mi = 0; mi < 4; ++mi) {
        f32x4 s0 = pA[cur][mi] + aiA[mi] + ajA[ng];
        f32x4 s1 = pB[cur][mi] + aiB[mi] + ajB[ng];
        union { uint32_t u[4]; short8 v; } ef;
        ef.u[0] = cvt_pk_bf16(fmaxf(s0[0], 0.f), fmaxf(s0[1], 0.f));
        ef.u[1] = cvt_pk_bf16(fmaxf(s0[2], 0.f), fmaxf(s0[3], 0.f));
        ef.u[2] = cvt_pk_bf16(fmaxf(s1[0], 0.f), fmaxf(s1[1], 0.f));
        ef.u[3] = cvt_pk_bf16(fmaxf(s1[2], 0.f), fmaxf(s1[3], 0.f));
        f32x4 d = __builtin_amdgcn_mfma_f32_16x16x32_bf16(w2f.v, ef.v, zero, 0, 0, 0);
        part[mi] = fmaxf(d[0], 0.f) * w3v[0] + fmaxf(d[1], 0.f) * w3v[1] +
                   fmaxf(d[2], 0.f) * w3v[2] + fmaxf(d[3], 0.f) * w3v[3];
      }
      // 3-shuffle butterfly reduce (validated r6/r7)
      float mineA = bit4 ? part[1] : part[0];
      float sendA = bit4 ? part[0] : part[1];
      float mineB = bit4 ? part[3] : part[2];
      float sendB = bit4 ? part[2] : part[3];
      mineA += __shfl_xor(sendA, 16, 64);
      mineB += __shfl_xor(sendB, 16, 64);
      float keep = bit5 ? mineB : mineA;
      float send = bit5 ? mineA : mineB;
      float res = keep + __shfl_xor(send, 32, 64);
      out_b[idxs[ng]] = av[ng] + res;
    }
  }
}

extern "C" void kernel_launch(void* const* d_in, const int* in_sizes, int n_in,
                              void* d_out, int out_size, void* d_ws, size_t ws_size,
                              hipStream_t stream) {
  const float* attn = (const float*)d_in[0];
  const int* bseq   = (const int*)d_in[1];
  const int* cseq   = (const int*)d_in[2];
  const float* epos = (const float*)d_in[3];
  const float* ebi  = (const float*)d_in[4];
  const float* ebj  = (const float*)d_in[5];
  const float* eci  = (const float*)d_in[6];
  const float* ecj  = (const float*)d_in[7];
  const float* w1   = (const float*)d_in[8];
  const float* w2   = (const float*)d_in[9];
  const float* w3   = (const float*)d_in[10];
  float* out = (float*)d_out;

  hipLaunchKernelGGL(dis_att_fused, dim3(512), dim3(512), 0, stream,
                     attn, bseq, cseq, epos, ebi, ebj, eci, ecj, w1, w2, w3, out);
}

// Round 12
// 25.663 us; speedup vs baseline: 1.0659x; 1.0444x over previous
//
#include <hip/hip_runtime.h>
#include <stdint.h>

typedef __attribute__((ext_vector_type(8))) short short8;
typedef __attribute__((ext_vector_type(4))) float f32x4;

#define SEQ 256
#define NH 8

__device__ __forceinline__ uint32_t cvt_pk_bf16(float lo, float hi) {
  uint32_t r;
  asm("v_cvt_pk_bf16_f32 %0, %1, %2" : "=v"(r) : "v"(lo), "v"(hi));
  return r;
}

__device__ __forceinline__ short8 pack8(f32x4 a, f32x4 b) {
  union { uint32_t u[4]; short8 v; } t;
  t.u[0] = cvt_pk_bf16(a[0], a[1]);
  t.u[1] = cvt_pk_bf16(a[2], a[3]);
  t.u[2] = cvt_pk_bf16(b[0], b[1]);
  t.u[3] = cvt_pk_bf16(b[2], b[3]);
  return t.v;
}

// ---------------------------------------------------------------------------
// Kernel TB: deduplicated table build via MFMA (r5-validated conventions).
//   Tpos[h][512][32]: f-rows; Ti[h][1024][32]: rows b*256+m; Tj likewise.
// 1280 wave-tasks: 8h x (32 pos-tiles | 64 i-tiles | 64 j-tiles), one
// 16-row x 32-k tile per wave (2 MFMAs). 320 blocks x 256 thr.
// ---------------------------------------------------------------------------
__global__ __launch_bounds__(256) void build_tables_mfma(
    const int* __restrict__ bseq, const int* __restrict__ cseq,
    const float* __restrict__ epos, const float* __restrict__ ebi,
    const float* __restrict__ ebj, const float* __restrict__ eci,
    const float* __restrict__ ecj, const float* __restrict__ w1,
    float* __restrict__ Tpos, float* __restrict__ Ti, float* __restrict__ Tj) {
  int lane = threadIdx.x & 63, w = threadIdx.x >> 6;
  int task = blockIdx.x * 4 + w;            // [0,1280)
  int lcol = lane & 15, kb = lane >> 4, k8 = kb * 8;
  f32x4 zero = {0.f, 0.f, 0.f, 0.f};

  if (task < 256) {                          // Tpos: h = task>>5, ft = task&31
    int h = task >> 5, ft = task & 31;
    short8 bf[2];
#pragma unroll
    for (int kt = 0; kt < 2; ++kt) {
      union { uint32_t u[4]; short8 v; } t;
#pragma unroll
      for (int r = 0; r < 4; ++r) {
        float lo = w1[(k8 + 2 * r) * 256 + (kt * 16 + lcol) * 8 + h];
        float hi = w1[(k8 + 2 * r + 1) * 256 + (kt * 16 + lcol) * 8 + h];
        t.u[r] = cvt_pk_bf16(lo, hi);
      }
      bf[kt] = t.v;
    }
    const float* ep = epos + ((ft * 16 + lcol) * NH + h) * 32 + k8;
    short8 af = pack8(*(const f32x4*)ep, *(const f32x4*)(ep + 4));
#pragma unroll
    for (int kt = 0; kt < 2; ++kt) {
      f32x4 d = __builtin_amdgcn_mfma_f32_16x16x32_bf16(af, bf[kt], zero, 0, 0, 0);
#pragma unroll
      for (int r = 0; r < 4; ++r)
        Tpos[h * 16384 + (ft * 16 + kb * 4 + r) * 32 + kt * 16 + lcol] = d[r];
    }
  } else {                                   // Ti (256..767) / Tj (768..1279)
    int isI = task < 768;
    int t2 = task - (isI ? 256 : 768);
    int h = t2 >> 6, bm = t2 & 63;           // tile rows = bm*16 .. +15
    int p0 = isI ? ((kb < 2 ? 32 : 48) + k8)    // W_i rows: 32..47 | 64..79
                 : ((kb < 2 ? 48 : 64) + k8);   // W_j rows: 48..63 | 80..95
    short8 bf[2];
#pragma unroll
    for (int kt = 0; kt < 2; ++kt) {
      union { uint32_t u[4]; short8 v; } t;
#pragma unroll
      for (int r = 0; r < 4; ++r) {
        float lo = w1[(p0 + 2 * r) * 256 + (kt * 16 + lcol) * 8 + h];
        float hi = w1[(p0 + 2 * r + 1) * 256 + (kt * 16 + lcol) * 8 + h];
        t.u[r] = cvt_pk_bf16(lo, hi);
      }
      bf[kt] = t.v;
    }
    int gm = bm * 16 + lcol;                 // = b*256 + m  (bseq/cseq flat)
    int bi = bseq[gm], ci = cseq[gm];
    const float* eB = isI ? ebi : ebj;
    const float* eC = isI ? eci : ecj;
    const float* src = (kb < 2) ? eB + (bi * NH + h) * 16 + k8
                                : eC + (ci * NH + h) * 16 + (k8 - 16);
    short8 af = pack8(*(const f32x4*)src, *(const f32x4*)(src + 4));
    float* T = isI ? Ti : Tj;
#pragma unroll
    for (int kt = 0; kt < 2; ++kt) {
      f32x4 d = __builtin_amdgcn_mfma_f32_16x16x32_bf16(af, bf[kt], zero, 0, 0, 0);
#pragma unroll
      for (int r = 0; r < 4; ++r)
        T[h * 32768 + (bm * 16 + kb * 4 + r) * 32 + kt * 16 + lcol] = d[r];
    }
  }
}

// ---------------------------------------------------------------------------
// Kernel MAIN: stage tables d_ws -> LDS (coalesced), then r7 phase 2
// verbatim (batched pA/pB + sched_barrier + butterfly reduce).
// Block = (b, h, 64m x 64n), 512 thr (8 waves), 512 blocks.
// ---------------------------------------------------------------------------
__global__ __launch_bounds__(512, 4) void dis_att_main(
    const float* __restrict__ attn, const float* __restrict__ w2,
    const float* __restrict__ w3, const float* __restrict__ Tpos,
    const float* __restrict__ Ti, const float* __restrict__ Tj,
    float* __restrict__ out) {
  __shared__ float sAp[127][36];
  __shared__ float sAi[64][36];
  __shared__ float sAj[64][36];
  int tid = threadIdx.x;
  int wg = blockIdx.x;                      // 512 = b(4) h(8) mt(4) nt(4)
  int nt = wg & 3, mt = (wg >> 2) & 3, h = (wg >> 4) & 7, b = wg >> 7;
  int m0 = mt * 64, n0 = nt * 64;
  int f0 = m0 - n0 + 193;                   // global f of sAp row 0 (1..385)

  {  // stage: 8 thr/row, f32x4 each
    int r = tid >> 3, q = tid & 7;
    const float* P = Tpos + h * 16384 + (f0 + r) * 32 + q * 4;
    *(f32x4*)&sAp[r][q * 4] = *(const f32x4*)P;
    if (r + 64 < 127)
      *(f32x4*)&sAp[r + 64][q * 4] = *(const f32x4*)(P + 64 * 32);
    *(f32x4*)&sAi[r][q * 4] =
        *(const f32x4*)(Ti + h * 32768 + (b * 256 + m0 + r) * 32 + q * 4);
    *(f32x4*)&sAj[r][q * 4] =
        *(const f32x4*)(Tj + h * 32768 + (b * 256 + n0 + r) * 32 + q * 4);
  }
  __syncthreads();

  int lane = tid & 63, w = tid >> 6;
  int lcol = lane & 15, kb = lane >> 4, k8 = kb * 8;
  f32x4 zero = {0.f, 0.f, 0.f, 0.f};

  union { uint32_t u[4]; short8 v; } w2f;   // A = w2^T: row=lcol, k=k8..k8+7
#pragma unroll
  for (int r = 0; r < 4; ++r) {
    float lo = w2[(k8 + 2 * r) * 128 + lcol * 8 + h];
    float hi = w2[(k8 + 2 * r + 1) * 128 + lcol * 8 + h];
    w2f.u[r] = cvt_pk_bf16(lo, hi);
  }
  float w3v[4];
#pragma unroll
  for (int r = 0; r < 4; ++r) w3v[r] = w3[(kb * 4 + r) * 8 + h];

  f32x4 ajA[4], ajB[4];
#pragma unroll
  for (int ng = 0; ng < 4; ++ng) {
    int nl = ng * 16 + lcol;
    ajA[ng] = *(const f32x4*)&sAj[nl][k8];
    ajB[ng] = *(const f32x4*)&sAj[nl][k8 + 4];
  }

  const float* attn_b = attn + (b * NH + h) * SEQ * SEQ;
  float* out_b = out + (b * NH + h) * SEQ * SEQ;
  int bit4 = kb & 1, bit5 = kb & 2;

#pragma unroll
  for (int s = 0; s < 2; ++s) {
    int mb = w * 8 + s * 4;
    float av[4];
    int idxs[4];
#pragma unroll
    for (int ng = 0; ng < 4; ++ng) {
      idxs[ng] = (m0 + mb + kb) * SEQ + n0 + ng * 16 + lcol;
      av[ng] = attn_b[idxs[ng]];
    }
    f32x4 aiA[4], aiB[4];
#pragma unroll
    for (int mi = 0; mi < 4; ++mi) {
      aiA[mi] = *(const f32x4*)&sAi[mb + mi][k8];
      aiB[mi] = *(const f32x4*)&sAi[mb + mi][k8 + 4];
    }
#pragma unroll
    for (int ng = 0; ng < 4; ++ng) {
      int nl = ng * 16 + lcol;
      f32x4 pA[4], pB[4];
#pragma unroll
      for (int mi = 0; mi < 4; ++mi) {
        int rl = mb + mi - nl + 63;
        pA[mi] = *(const f32x4*)&sAp[rl][k8];
        pB[mi] = *(const f32x4*)&sAp[rl][k8 + 4];
      }
      __builtin_amdgcn_sched_barrier(0);
      float part[4];
#pragma unroll
      for (int mi = 0; mi < 4; ++mi) {
        f32x4 s0 = pA[mi] + aiA[mi] + ajA[ng];
        f32x4 s1 = pB[mi] + aiB[mi] + ajB[ng];
        union { uint32_t u[4]; short8 v; } ef;
        ef.u[0] = cvt_pk_bf16(fmaxf(s0[0], 0.f), fmaxf(s0[1], 0.f));
        ef.u[1] = cvt_pk_bf16(fmaxf(s0[2], 0.f), fmaxf(s0[3], 0.f));
        ef.u[2] = cvt_pk_bf16(fmaxf(s1[0], 0.f), fmaxf(s1[1], 0.f));
        ef.u[3] = cvt_pk_bf16(fmaxf(s1[2], 0.f), fmaxf(s1[3], 0.f));
        f32x4 d = __builtin_amdgcn_mfma_f32_16x16x32_bf16(w2f.v, ef.v, zero, 0, 0, 0);
        part[mi] = fmaxf(d[0], 0.f) * w3v[0] + fmaxf(d[1], 0.f) * w3v[1] +
                   fmaxf(d[2], 0.f) * w3v[2] + fmaxf(d[3], 0.f) * w3v[3];
      }
      float mineA = bit4 ? part[1] : part[0];
      float sendA = bit4 ? part[0] : part[1];
      float mineB = bit4 ? part[3] : part[2];
      float sendB = bit4 ? part[2] : part[3];
      mineA += __shfl_xor(sendA, 16, 64);
      mineB += __shfl_xor(sendB, 16, 64);
      float keep = bit5 ? mineB : mineA;
      float send = bit5 ? mineA : mineB;
      float res = keep + __shfl_xor(send, 32, 64);
      out_b[idxs[ng]] = av[ng] + res;
    }
  }
}

extern "C" void kernel_launch(void* const* d_in, const int* in_sizes, int n_in,
                              void* d_out, int out_size, void* d_ws, size_t ws_size,
                              hipStream_t stream) {
  const float* attn = (const float*)d_in[0];
  const int* bseq   = (const int*)d_in[1];
  const int* cseq   = (const int*)d_in[2];
  const float* epos = (const float*)d_in[3];
  const float* ebi  = (const float*)d_in[4];
  const float* ebj  = (const float*)d_in[5];
  const float* eci  = (const float*)d_in[6];
  const float* ecj  = (const float*)d_in[7];
  const float* w1   = (const float*)d_in[8];
  const float* w2   = (const float*)d_in[9];
  const float* w3   = (const float*)d_in[10];
  float* out = (float*)d_out;

  float* Tpos = (float*)d_ws;              // 8*512*32  = 131072 f32
  float* Ti   = Tpos + 131072;             // 8*1024*32 = 262144 f32
  float* Tj   = Ti + 262144;               // 262144 f32  (total 2.62 MB)

  hipLaunchKernelGGL(build_tables_mfma, dim3(320), dim3(256), 0, stream,
                     bseq, cseq, epos, ebi, ebj, eci, ecj, w1, Tpos, Ti, Tj);
  hipLaunchKernelGGL(dis_att_main, dim3(512), dim3(512), 0, stream,
                     attn, w2, w3, Tpos, Ti, Tj, out);
}